// Round 6
// baseline (40.224 us; speedup 1.0000x reference)
//
#include <hip/hip_runtime.h>
#include <hip/hip_bf16.h>
#include <stdint.h>

#define B_ROWS 8192
#define D_DIM  128
#define TILE   128
#define NT     64            // tiles per dimension
#define NCR    4             // column ranges (persistent blocks per row-tile)
#define CT_PER_BLK 16        // column tiles per block

typedef __attribute__((ext_vector_type(8))) __bf16 bf16x8;
typedef __attribute__((ext_vector_type(4))) float  f32x4;

typedef __attribute__((address_space(3))) uint32_t lds_u32;
typedef __attribute__((address_space(1))) const uint32_t glb_u32;

__device__ __forceinline__ float fast_exp2(float x) {
    float r;
    asm("v_exp_f32 %0, %1" : "=v"(r) : "v"(x));
    return r;
}

// ---------------- Kernel 1: l2-normalize rows, cast to bf16 ----------------
__global__ void k_norm(const float* __restrict__ z, __hip_bfloat16* __restrict__ zn) {
    int row  = blockIdx.x * 4 + (threadIdx.x >> 6);
    int lane = threadIdx.x & 63;
    const float2 v = reinterpret_cast<const float2*>(z + (size_t)row * D_DIM)[lane];
    float ss = v.x * v.x + v.y * v.y;
    #pragma unroll
    for (int m = 1; m < 64; m <<= 1) ss += __shfl_xor(ss, m);
    float inv = rsqrtf(fmaxf(ss, 1e-12f));
    __hip_bfloat162 o;
    o.x = __float2bfloat16(v.x * inv);
    o.y = __float2bfloat16(v.y * inv);
    reinterpret_cast<__hip_bfloat162*>(zn + (size_t)row * D_DIM)[lane] = o;
}

// ---------------- Kernel 2: persistent-tile similarity, counted-vmcnt pipe --
// 256 blocks (1/CU). Block = (rt, 16 cts). A staged once; B triple-buffered.
// T3/T4: raw s_barrier + s_waitcnt vmcnt(8) — loads stay in flight across
// barriers; vmcnt never drains to 0 in the main loop.
// Swizzle identical to R4/R5 (validated): linear LDS dest for global_load_lds,
// inverse-XOR global source, XOR-swizzled ds_read_b128.
__global__ __launch_bounds__(512, 2) void k_sim(const __bf16* __restrict__ zn,
                                                float* __restrict__ s_partial,
                                                float* __restrict__ pos) {
    __shared__ __align__(16) char smem[32768 * 4 + TILE * 4 * sizeof(float)];
    char* sA = smem;                     // 32 KB, written once
    char* sB = smem + 32768;             // 3 x 32 KB rotating buffers
    float (*red)[4] = (float (*)[4])(smem + 32768 * 4);

    const int tid  = threadIdx.x;
    const int lane = tid & 63;
    const int l15  = lane & 15;
    const int lg   = lane >> 4;          // 0..3
    const int w    = tid >> 6;           // 0..7
    const int wr   = w >> 2;             // 0..1 : rows [wr*64, +64)
    const int wc   = w & 3;              // 0..3 : cols [wc*32, +32)
    const int rt   = blockIdx.x >> 2;    // 0..63
    const int cr   = blockIdx.x & 3;     // 0..3
    const int ct0  = cr * CT_PER_BLK;

    // stage a 128-row tile (32 KB): 4x 16B per thread; involution u ^= row&7
    auto stage = [&](int gRowBase, char* dst) {
        #pragma unroll
        for (int j = 0; j < 4; ++j) {
            int slot = j * 512 + tid;
            int row  = slot >> 4;
            int u    = slot & 15;
            const __bf16* g = zn + (size_t)(gRowBase + row) * D_DIM + ((u ^ (row & 7)) << 3);
            __builtin_amdgcn_global_load_lds((glb_u32*)g, (lds_u32*)(dst + slot * 16), 16, 0, 0);
        }
    };

    const float C1 = 2.0f * 1.4426950408889634f;   // sim = 2*dot (tau = 0.5)
    const float C0 = -2.0f * 1.4426950408889634f;  // exp(sim-2) = exp2(dot*C1+C0)
    float srow[4][4];
    #pragma unroll
    for (int t = 0; t < 4; ++t)
        #pragma unroll
        for (int r = 0; r < 4; ++r) srow[t][r] = 0.f;

    // compute one 128x128 tile from LDS buffer bb (B side); A from sA
    auto computeTile = [&](int ct, const char* bb) {
        bf16x8 bfr[2][4];
        #pragma unroll
        for (int cs = 0; cs < 2; ++cs)
            #pragma unroll
            for (int ks = 0; ks < 4; ++ks) {
                int row = wc * 32 + cs * 16 + l15;
                int kb  = ks * 64 + lg * 16;
                bfr[cs][ks] = *reinterpret_cast<const bf16x8*>(
                    bb + row * 256 + (kb ^ ((row & 7) << 4)));
            }
        const bool diagTile = (ct == rt);
        #pragma unroll
        for (int t = 0; t < 4; ++t) {
            bf16x8 afr[4];
            #pragma unroll
            for (int ks = 0; ks < 4; ++ks) {
                int row = wr * 64 + t * 16 + l15;
                int kb  = ks * 64 + lg * 16;
                afr[ks] = *reinterpret_cast<const bf16x8*>(
                    sA + row * 256 + (kb ^ ((row & 7) << 4)));
            }
            #pragma unroll
            for (int cs = 0; cs < 2; ++cs) {
                f32x4 acc = {0.f, 0.f, 0.f, 0.f};
                #pragma unroll
                for (int ks = 0; ks < 4; ++ks)
                    acc = __builtin_amdgcn_mfma_f32_16x16x32_bf16(afr[ks], bfr[cs][ks], acc, 0, 0, 0);

                if (diagTile && (wr * 64 + t * 16 == wc * 32 + cs * 16)) {
                    const int fragBase = rt * TILE + wr * 64 + t * 16;
                    const int col = fragBase + l15;
                    #pragma unroll
                    for (int r = 0; r < 4; ++r) {
                        int row = fragBase + lg * 4 + r;
                        float e = fast_exp2(fmaf(acc[r], C1, C0));
                        if (col == row) e = 0.f;                         // mask self
                        if (col == (row ^ 1)) pos[row] = acc[r] * 2.0f;  // partner sim
                        srow[t][r] += e;
                    }
                } else {
                    #pragma unroll
                    for (int r = 0; r < 4; ++r)
                        srow[t][r] += fast_exp2(fmaf(acc[r], C1, C0));
                }
            }
        }
    };

    // ---- prologue: A + 3 B tiles in flight; wait only for A+B0
    stage(rt * TILE, sA);
    stage((ct0 + 0) * TILE, sB);
    stage((ct0 + 1) * TILE, sB + 32768);
    stage((ct0 + 2) * TILE, sB + 65536);
    asm volatile("s_waitcnt vmcnt(8)" ::: "memory");   // A,B0 landed; B1,B2 in flight
    __builtin_amdgcn_s_barrier();

    // ---- main loop: i = 0..12, stage B_{i+3} into the buffer being vacated
    #pragma unroll 1
    for (int i = 0; i < 13; ++i) {
        char* bb = sB + (i % 3) * 32768;
        // pre-read this tile's B fragments (B_i guaranteed landed)
        bf16x8 keep[2][4];
        #pragma unroll
        for (int cs = 0; cs < 2; ++cs)
            #pragma unroll
            for (int ks = 0; ks < 4; ++ks) {
                int row = wc * 32 + cs * 16 + l15;
                int kb  = ks * 64 + lg * 16;
                keep[cs][ks] = *reinterpret_cast<const bf16x8*>(
                    bb + row * 256 + (kb ^ ((row & 7) << 4)));
            }
        asm volatile("s_waitcnt lgkmcnt(0)" ::: "memory");
        __builtin_amdgcn_sched_barrier(0);
        __builtin_amdgcn_s_barrier();         // all waves done reading bb
        __builtin_amdgcn_sched_barrier(0);
        stage((ct0 + i + 3) * TILE, bb);      // overwrite freed buffer

        // compute tile i using the pre-read fragments
        {
            const int ct = ct0 + i;
            const bool diagTile = (ct == rt);
            #pragma unroll
            for (int t = 0; t < 4; ++t) {
                bf16x8 afr[4];
                #pragma unroll
                for (int ks = 0; ks < 4; ++ks) {
                    int row = wr * 64 + t * 16 + l15;
                    int kb  = ks * 64 + lg * 16;
                    afr[ks] = *reinterpret_cast<const bf16x8*>(
                        sA + row * 256 + (kb ^ ((row & 7) << 4)));
                }
                #pragma unroll
                for (int cs = 0; cs < 2; ++cs) {
                    f32x4 acc = {0.f, 0.f, 0.f, 0.f};
                    #pragma unroll
                    for (int ks = 0; ks < 4; ++ks)
                        acc = __builtin_amdgcn_mfma_f32_16x16x32_bf16(afr[ks], keep[cs][ks], acc, 0, 0, 0);
                    if (diagTile && (wr * 64 + t * 16 == wc * 32 + cs * 16)) {
                        const int fragBase = rt * TILE + wr * 64 + t * 16;
                        const int col = fragBase + l15;
                        #pragma unroll
                        for (int r = 0; r < 4; ++r) {
                            int row = fragBase + lg * 4 + r;
                            float e = fast_exp2(fmaf(acc[r], C1, C0));
                            if (col == row) e = 0.f;
                            if (col == (row ^ 1)) pos[row] = acc[r] * 2.0f;
                            srow[t][r] += e;
                        }
                    } else {
                        #pragma unroll
                        for (int r = 0; r < 4; ++r)
                            srow[t][r] += fast_exp2(fmaf(acc[r], C1, C0));
                    }
                }
            }
        }
        asm volatile("s_waitcnt vmcnt(8)" ::: "memory");  // B_{i+1} landed
        __builtin_amdgcn_s_barrier();
    }

    // ---- tail: i = 13,14,15 (no more stages; drain gradually)
    computeTile(ct0 + 13, sB + 32768);                 // 13 % 3 = 1
    asm volatile("s_waitcnt vmcnt(4)" ::: "memory");   // B14 landed
    __builtin_amdgcn_s_barrier();
    computeTile(ct0 + 14, sB + 65536);                 // 14 % 3 = 2
    asm volatile("s_waitcnt vmcnt(0)" ::: "memory");   // B15 landed
    __builtin_amdgcn_s_barrier();
    computeTile(ct0 + 15, sB);                         // 15 % 3 = 0

    // ---- final reduction: 16 lanes sharing a row -> cross-wave (wc) via LDS
    __syncthreads();
    #pragma unroll
    for (int t = 0; t < 4; ++t)
        #pragma unroll
        for (int r = 0; r < 4; ++r) {
            float v = srow[t][r];
            v += __shfl_xor(v, 1);
            v += __shfl_xor(v, 2);
            v += __shfl_xor(v, 4);
            v += __shfl_xor(v, 8);
            if (l15 == 0) red[wr * 64 + t * 16 + lg * 4 + r][wc] = v;
        }
    __syncthreads();
    if (tid < TILE) {
        float v = red[tid][0] + red[tid][1] + red[tid][2] + red[tid][3];
        s_partial[(size_t)cr * B_ROWS + rt * TILE + tid] = v;
    }
}

// ---------------- Kernel 3: per-row loss, per-block partial sums ------------
__global__ void k_loss_partial(const float* __restrict__ sp,
                               const float* __restrict__ pos,
                               float* __restrict__ part) {
    int i = blockIdx.x * 256 + threadIdx.x;
    float ssum = sp[i] + sp[B_ROWS + i] + sp[2 * B_ROWS + i] + sp[3 * B_ROWS + i];
    float v = 2.0f + logf(ssum) - pos[i];
    #pragma unroll
    for (int m = 1; m < 64; m <<= 1) v += __shfl_xor(v, m);
    __shared__ float ls[4];
    if ((threadIdx.x & 63) == 0) ls[threadIdx.x >> 6] = v;
    __syncthreads();
    if (threadIdx.x == 0) part[blockIdx.x] = ls[0] + ls[1] + ls[2] + ls[3];
}

// ---------------- Kernel 4: final reduce ------------------------------------
__global__ void k_final(const float* __restrict__ part, float* __restrict__ out) {
    float v = (threadIdx.x < (B_ROWS / 256)) ? part[threadIdx.x] : 0.f;
    #pragma unroll
    for (int m = 1; m < 64; m <<= 1) v += __shfl_xor(v, m);
    if (threadIdx.x == 0) out[0] = v * (1.0f / (float)B_ROWS);
}

extern "C" void kernel_launch(void* const* d_in, const int* in_sizes, int n_in,
                              void* d_out, int out_size, void* d_ws, size_t ws_size,
                              hipStream_t stream) {
    const float* z = (const float*)d_in[0];
    float* out = (float*)d_out;

    char* ws = (char*)d_ws;
    __hip_bfloat16* zn = (__hip_bfloat16*)ws;                            // 2 MB
    float* s_partial = (float*)(ws + (size_t)B_ROWS * D_DIM * 2);        // 128 KB
    float* pos  = (float*)((char*)s_partial + (size_t)NCR * B_ROWS * 4); // 32 KB
    float* part = (float*)((char*)pos + (size_t)B_ROWS * 4);             // 128 B

    // 1) normalize + bf16 cast
    k_norm<<<B_ROWS / 4, 256, 0, stream>>>(z, zn);

    // 2) persistent similarity: 64 row-tiles x 4 col-ranges = 256 blocks (1/CU)
    k_sim<<<NT * NCR, 512, 0, stream>>>((const __bf16*)zn, s_partial, pos);

    // 3) per-row loss -> 32 block partials
    k_loss_partial<<<B_ROWS / 256, 256, 0, stream>>>(s_partial, pos, part);

    // 4) final scalar
    k_final<<<1, 64, 0, stream>>>(part, out);
}